// Round 3
// baseline (46031.253 us; speedup 1.0000x reference)
//
#include <hip/hip_runtime.h>
#include <hip/hip_bf16.h>

#define SEQ 2048
#define NB  64
#define NIN 128
#define NH  256
// A-term layout: [t][group][gate*16+ntile][lane][q] bf16  (48 chunks of 256/tg)
#define AT_PER_TG 12288
#define HSTRIDE 296   // 148 dwords == 20 (mod 32): spreads column-slice writes

typedef __bf16 bf16x8 __attribute__((ext_vector_type(8)));
typedef __bf16 bf16x4 __attribute__((ext_vector_type(4)));
typedef float  f32x4  __attribute__((ext_vector_type(4)));

#define MFMA16 __builtin_amdgcn_mfma_f32_16x16x32_bf16

__device__ __forceinline__ float fast_sigmoid(float x) {
    float e = __builtin_amdgcn_exp2f(-1.4426950408889634f * x);
    return __builtin_amdgcn_rcpf(1.0f + e);
}
__device__ __forceinline__ float fast_tanh(float x) {
    float e = __builtin_amdgcn_exp2f(2.8853900817779268f * x);
    return 1.0f - 2.0f * __builtin_amdgcn_rcpf(1.0f + e);
}

// ---------- phase 1: A-terms = x @ Wg_x^T  (frag-ordered bf16) -------------
__global__ __launch_bounds__(256) void gru_pre(
        const float* __restrict__ x, const float* __restrict__ Wz,
        const float* __restrict__ Wr, const float* __restrict__ Wi,
        __bf16* __restrict__ At) {
    __shared__ __align__(16) __bf16 wlds[256][136];
    __shared__ __align__(16) __bf16 xlds[64][136];
    const int bid = blockIdx.x;
    const int t = bid / 3, gate = bid - t * 3;
    const float* W = (gate == 0) ? Wz : ((gate == 1) ? Wr : Wi);
    const int xoff = (gate == 2) ? NH : 0;   // Wi is [h, x] (hidden-first)
    const int tid = threadIdx.x;
    #pragma unroll
    for (int j = 0; j < 32; ++j) {
        int flat = j * 1024 + tid * 4;
        int row = flat >> 7, col = flat & 127;
        const float4 v = *(const float4*)(W + (size_t)row * 384 + xoff + col);
        wlds[row][col+0] = (__bf16)v.x; wlds[row][col+1] = (__bf16)v.y;
        wlds[row][col+2] = (__bf16)v.z; wlds[row][col+3] = (__bf16)v.w;
    }
    const float* xt = x + (size_t)t * (NB * NIN);
    #pragma unroll
    for (int j = 0; j < 8; ++j) {
        int flat = j * 1024 + tid * 4;
        int row = flat >> 7, col = flat & 127;
        const float4 v = *(const float4*)(xt + row * NIN + col);
        xlds[row][col+0] = (__bf16)v.x; xlds[row][col+1] = (__bf16)v.y;
        xlds[row][col+2] = (__bf16)v.z; xlds[row][col+3] = (__bf16)v.w;
    }
    __syncthreads();
    const int wv = tid >> 6, l = tid & 63;
    const int lrow = l & 15, lk = (l >> 4) * 8;
    bf16x8 a[4];
    #pragma unroll
    for (int kt = 0; kt < 4; ++kt)
        a[kt] = *(const bf16x8*)&xlds[wv * 16 + lrow][kt * 32 + lk];
    #pragma unroll
    for (int j = 0; j < 16; ++j) {
        f32x4 acc = {0.f, 0.f, 0.f, 0.f};
        #pragma unroll
        for (int kt = 0; kt < 4; ++kt) {
            bf16x8 b = *(const bf16x8*)&wlds[j * 16 + lrow][kt * 32 + lk];
            acc = MFMA16(a[kt], b, acc, 0, 0, 0);
        }
        size_t off = (size_t)(t * 4 + wv) * AT_PER_TG
                   + (size_t)((gate * 16 + j) * 256 + l * 4);
        bf16x4 o;
        o[0]=(__bf16)acc[0]; o[1]=(__bf16)acc[1]; o[2]=(__bf16)acc[2]; o[3]=(__bf16)acc[3];
        *(bf16x4*)(At + off) = o;
    }
}

// ---------- phase 2: recurrence. 4 blocks x 256 thr (4 waves, 1 wave/SIMD) --
// 512-reg unified budget/wave: Wz,Wr (64 frags) in the 256 AGPRs, Wi (32
// frags) in VGPRs, ~125 VGPRs of working set. Pins are loop-carried so the
// compiler cannot rematerialize/spill the weights.
#define DECLW(p) f32x4 W##p##0, W##p##1, W##p##2, W##p##3, W##p##4, W##p##5, W##p##6, W##p##7

#define LDW1(dst, base, kt) do { \
    const float4 v0_ = *(const float4*)((base) + (kt)*32 + lk); \
    const float4 v1_ = *(const float4*)((base) + (kt)*32 + lk + 4); \
    bf16x8 f_; \
    f_[0]=(__bf16)v0_.x; f_[1]=(__bf16)v0_.y; f_[2]=(__bf16)v0_.z; f_[3]=(__bf16)v0_.w; \
    f_[4]=(__bf16)v1_.x; f_[5]=(__bf16)v1_.y; f_[6]=(__bf16)v1_.z; f_[7]=(__bf16)v1_.w; \
    dst = __builtin_bit_cast(f32x4, f_); } while (0)

#define LDW8(p, base) do { LDW1(W##p##0,base,0); LDW1(W##p##1,base,1); \
    LDW1(W##p##2,base,2); LDW1(W##p##3,base,3); LDW1(W##p##4,base,4); \
    LDW1(W##p##5,base,5); LDW1(W##p##6,base,6); LDW1(W##p##7,base,7); } while (0)

#define PINA8(p) asm volatile("" : "+a"(W##p##0), "+a"(W##p##1), "+a"(W##p##2), \
    "+a"(W##p##3), "+a"(W##p##4), "+a"(W##p##5), "+a"(W##p##6), "+a"(W##p##7))
#define PINV8(p) asm volatile("" : "+v"(W##p##0), "+v"(W##p##1), "+v"(W##p##2), \
    "+v"(W##p##3), "+v"(W##p##4), "+v"(W##p##5), "+v"(W##p##6), "+v"(W##p##7))

#define BW(p,k) __builtin_bit_cast(bf16x8, W##p##k)

#define AINIT(dst, c) do { bf16x4 tv_ = __builtin_bit_cast(bf16x4, pf[c]); \
    dst[0]=(float)tv_[0]; dst[1]=(float)tv_[1]; dst[2]=(float)tv_[2]; dst[3]=(float)tv_[3]; } while (0)

#define ASTEP(kt) do { bf16x8 ha_ = *(const bf16x8*)&hB[lrow][(kt)*32 + lk]; \
    az0 = MFMA16(ha_, BW(z0,kt), az0,0,0,0); az1 = MFMA16(ha_, BW(z1,kt), az1,0,0,0); \
    az2 = MFMA16(ha_, BW(z2,kt), az2,0,0,0); az3 = MFMA16(ha_, BW(z3,kt), az3,0,0,0); \
    ar0 = MFMA16(ha_, BW(r0,kt), ar0,0,0,0); ar1 = MFMA16(ha_, BW(r1,kt), ar1,0,0,0); \
    ar2 = MFMA16(ha_, BW(r2,kt), ar2,0,0,0); ar3 = MFMA16(ha_, BW(r3,kt), ar3,0,0,0); } while (0)

#define ISTEP(kt) do { bf16x8 ra_ = *(const bf16x8*)&rhB[lrow][(kt)*32 + lk]; \
    ai0 = MFMA16(ra_, BW(i0,kt), ai0,0,0,0); ai1 = MFMA16(ra_, BW(i1,kt), ai1,0,0,0); \
    ai2 = MFMA16(ra_, BW(i2,kt), ai2,0,0,0); ai3 = MFMA16(ra_, BW(i3,kt), ai3,0,0,0); } while (0)

#define ACT_A(m, accz, accr) do { _Pragma("unroll") for (int q = 0; q < 4; ++q) { \
    float rv_ = fast_sigmoid(accr[q]); \
    rhB[crow + q][col0 + (m)*16] = (__bf16)(rv_ * h[m][q]); \
    zv[m][q] = fast_sigmoid(accz[q]); } } while (0)

#define ACT_B(m, acci) do { _Pragma("unroll") for (int q = 0; q < 4; ++q) { \
    float it_ = fast_tanh(acci[q]); \
    float hn_ = h[m][q] + zv[m][q] * (it_ - h[m][q]); \
    h[m][q] = hn_; \
    ot[(size_t)q * NH + (m)*16] = hn_; \
    hB[crow + q][col0 + (m)*16] = (__bf16)hn_; } } while (0)

__global__ __launch_bounds__(256, 1) void gru_rec(
        const float* __restrict__ h0, const float* __restrict__ Wz,
        const float* __restrict__ Wr, const float* __restrict__ Wi,
        const __bf16* __restrict__ At, float* __restrict__ out) {
    __shared__ __align__(16) __bf16 hB[16][HSTRIDE];
    __shared__ __align__(16) __bf16 rhB[16][HSTRIDE];
    const int g = blockIdx.x;
    const int tid = threadIdx.x;
    const int wv = tid >> 6, l = tid & 63;
    const int lrow = l & 15;       // A row / C col
    const int lk = (l >> 4) * 8;   // k-slice base
    const int crow = (l >> 4) * 4; // C row base
    const int col0 = wv * 64 + lrow;   // this wave's output cols: col0 + m*16

    // ---- weights: z,r -> AGPR (exactly 256); i -> VGPR (128) ----
    DECLW(z0); DECLW(z1); DECLW(z2); DECLW(z3);
    DECLW(r0); DECLW(r1); DECLW(r2); DECLW(r3);
    DECLW(i0); DECLW(i1); DECLW(i2); DECLW(i3);
    {
        const float* bz = Wz + (size_t)col0 * 384 + 128;   // h-part cols of Wz
        LDW8(z0, bz); LDW8(z1, bz + 16*384); LDW8(z2, bz + 32*384); LDW8(z3, bz + 48*384);
        const float* br = Wr + (size_t)col0 * 384 + 128;
        LDW8(r0, br); LDW8(r1, br + 16*384); LDW8(r2, br + 32*384); LDW8(r3, br + 48*384);
        const float* bi = Wi + (size_t)col0 * 384;          // Wi hidden-first
        LDW8(i0, bi); LDW8(i1, bi + 16*384); LDW8(i2, bi + 32*384); LDW8(i3, bi + 48*384);
    }

    // ---- init h (f32 regs, C-frag coords) + hB ----
    float h[4][4];
    #pragma unroll
    for (int m = 0; m < 4; ++m)
        #pragma unroll
        for (int q = 0; q < 4; ++q) {
            float v = h0[(size_t)(g * 16 + crow + q) * NH + col0 + m * 16];
            h[m][q] = v;
            hB[crow + q][col0 + m * 16] = (__bf16)v;
        }

    // ---- A-term register prefetch: 12 x uint2 (bf16x4) per thread ----
    uint2 pf[12];
    {
        const __bf16* p0 = At + (size_t)g * AT_PER_TG;
        #pragma unroll
        for (int c = 0; c < 12; ++c)
            pf[c] = *(const uint2*)(p0 + ((c >> 2) * 16 + wv * 4 + (c & 3)) * 256 + l * 4);
    }
    asm volatile("s_waitcnt lgkmcnt(0)" ::: "memory");
    __builtin_amdgcn_s_barrier();

    float* outp = out + (size_t)(g * 16 + crow) * NH + col0;

    #pragma clang loop unroll(disable)
    for (int t = 0; t < SEQ; ++t) {
        // loop-carried pins: weights cannot be rematerialized or spilled
        PINA8(z0); PINA8(z1); PINA8(z2); PINA8(z3);
        PINA8(r0); PINA8(r1); PINA8(r2); PINA8(r3);
        PINV8(i0); PINV8(i1); PINV8(i2); PINV8(i3);

        // ---- phase A: z,r GEMMs; acc init from prefetched x-terms ----
        f32x4 az0, az1, az2, az3, ar0, ar1, ar2, ar3;
        AINIT(az0, 0); AINIT(az1, 1); AINIT(az2, 2); AINIT(az3, 3);
        AINIT(ar0, 4); AINIT(ar1, 5); AINIT(ar2, 6); AINIT(ar3, 7);
        ASTEP(0); ASTEP(1); ASTEP(2); ASTEP(3);
        ASTEP(4); ASTEP(5); ASTEP(6); ASTEP(7);

        float zv[4][4];
        ACT_A(0, az0, ar0); ACT_A(1, az1, ar1); ACT_A(2, az2, ar2); ACT_A(3, az3, ar3);
        asm volatile("s_waitcnt lgkmcnt(0)" ::: "memory");
        __builtin_amdgcn_s_barrier();

        // ---- phase B: inter GEMM on (r*h) ----
        f32x4 ai0, ai1, ai2, ai3;
        AINIT(ai0, 8); AINIT(ai1, 9); AINIT(ai2, 10); AINIT(ai3, 11);
        // prefetch A-terms for t+1 (clamped at tail)
        {
            const int tp = (t + 1 < SEQ) ? (t + 1) : (SEQ - 1);
            const __bf16* pfp = At + (size_t)(tp * 4 + g) * AT_PER_TG;
            #pragma unroll
            for (int c = 0; c < 12; ++c)
                pf[c] = *(const uint2*)(pfp + ((c >> 2) * 16 + wv * 4 + (c & 3)) * 256 + l * 4);
        }
        ISTEP(0); ISTEP(1); ISTEP(2); ISTEP(3);
        ISTEP(4); ISTEP(5); ISTEP(6); ISTEP(7);

        // ---- tanh, blend, store out + hB for next step ----
        float* ot = outp;
        ACT_B(0, ai0); ACT_B(1, ai1); ACT_B(2, ai2); ACT_B(3, ai3);
        outp += NB * NH;
        asm volatile("s_waitcnt lgkmcnt(0)" ::: "memory");
        __builtin_amdgcn_s_barrier();
    }
}

extern "C" void kernel_launch(void* const* d_in, const int* in_sizes, int n_in,
                              void* d_out, int out_size, void* d_ws, size_t ws_size,
                              hipStream_t stream) {
    const float* x  = (const float*)d_in[0];
    const float* h0 = (const float*)d_in[1];
    const float* Wz = (const float*)d_in[2];
    const float* Wr = (const float*)d_in[3];
    const float* Wi = (const float*)d_in[4];
    __bf16* At = (__bf16*)d_ws;   // SEQ*4*AT_PER_TG*2 = 192 MiB
    (void)in_sizes; (void)n_in; (void)out_size; (void)ws_size;

    gru_pre<<<dim3(SEQ * 3), dim3(256), 0, stream>>>(x, Wz, Wr, Wi, At);
    gru_rec<<<dim3(4), dim3(256), 0, stream>>>(h0, Wz, Wr, Wi, At, (float*)d_out);
}